// Round 6
// baseline (16.140 us; speedup 1.0000x reference)
//
#include <hip/hip_runtime.h>
#include <hip/hip_bf16.h>

#define NPOS   1024
#define NBATCH 4
#define BT     64    // kernel-2 output tile (both dims)
#define KD     128   // K dim in halves (64 feats x cos/sin)
#define ROWB   256   // bytes per A/B row (128 halves)

typedef _Float16 half8  __attribute__((ext_vector_type(8)));
typedef _Float16 half2x __attribute__((ext_vector_type(2)));
typedef float    floatx4 __attribute__((ext_vector_type(4)));

#define INV2PI 0.15915494309189535f

// out[b,i,j] = sum_f a_f*cos(10*(x_j-x_i)*w_f + b_f) = <A[i,:], B[j,:]>, K=128
// A[p,2f]=cos(t_p) A[p,2f+1]=sin(t_p); B[p,2f]=a_f cos(t_p+b_f), B[p,2f+1]=a_f sin(..)
// K order = (cos,sin) interleaved (dot product invariant under K-permutation).
// Trig in revolutions (native v_sin/v_cos); |args| <= ~1.8 rev, no reduction.
//
// R6: producer/consumer split.
//  k1: A/B for all (b,pos,f) once (0.5M sincos) -> d_ws, PRE-SWIZZLED
//      (byte_in_row ^= (pos&7)<<4) so k2 stages with linear global_load_lds
//      and reads LDS conflict-free (16-way -> 2-way).
//  k2: pure GEMM: 8x global_load_lds_dwordx4 (32KB from L2/L3), barrier,
//      hoisted fragments, 32 MFMA, interleaved stores. 4 WG/CU.

__device__ __forceinline__ void gload_lds16(const void* g, void* l) {
    __builtin_amdgcn_global_load_lds(
        (const __attribute__((address_space(1))) void*)g,
        (__attribute__((address_space(3))) void*)l, 16, 0, 0);
}

// ---------------- kernel 1: trig producer ----------------
__global__ __launch_bounds__(256)
void trig_kernel(const float* __restrict__ frac, const float* __restrict__ Wv,
                 const float* __restrict__ bv,   const float* __restrict__ av,
                 _Float16* __restrict__ wsA, _Float16* __restrict__ wsB) {
    const int g = blockIdx.x * 256 + threadIdx.x;   // 1024 WGs x 256
    const int f = g & 63;
    const int p = (g >> 6) & (NPOS - 1);
    const int b = g >> 16;                          // 0..3
    const float x  = frac[(b << 10) + p];           // wave-uniform
    const float wf = Wv[f] * (10.0f * INV2PI);
    const float bf = bv[f] * INV2PI;
    const float af = av[f];

    const unsigned rowbase = (unsigned)(((b << 10) + p) * ROWB);
    const unsigned off     = ((unsigned)(f * 4)) ^ (((unsigned)(p & 7)) << 4);

    const float ai = x * wf;
    half2x pa;
    pa[0] = (_Float16)__builtin_amdgcn_cosf(ai);
    pa[1] = (_Float16)__builtin_amdgcn_sinf(ai);
    *reinterpret_cast<half2x*>(reinterpret_cast<char*>(wsA) + rowbase + off) = pa;

    const float aj = __builtin_fmaf(x, wf, bf);
    half2x pb;
    pb[0] = (_Float16)(af * __builtin_amdgcn_cosf(aj));
    pb[1] = (_Float16)(af * __builtin_amdgcn_sinf(aj));
    *reinterpret_cast<half2x*>(reinterpret_cast<char*>(wsB) + rowbase + off) = pb;
}

// ---------------- kernel 2: GEMM consumer ----------------
__global__ __launch_bounds__(256, 4)
void gemm_kernel(const _Float16* __restrict__ wsA, const _Float16* __restrict__ wsB,
                 float* __restrict__ out) {
    __shared__ _Float16 sA[BT * KD];   // 16 KB, linear (holds swizzled rows)
    __shared__ _Float16 sB[BT * KD];   // 16 KB

    // XCD-contiguous bijective swizzle (1024 = 8*128)
    int wg = blockIdx.x;
    wg = (wg & 7) * 128 + (wg >> 3);
    const int bz  = wg >> 8;
    const int rem = wg & 255;
    const int ti  = (rem >> 4) * BT;
    const int tj  = (rem & 15) * BT;

    const int tid  = threadIdx.x;
    const int lane = tid & 63;
    const int wid  = tid >> 6;

    // ---- stage A/B tiles: 16KB each = 16 chunks of 1KB; wave w does chunks w*4..w*4+3
    const char* gA = reinterpret_cast<const char*>(wsA) + (size_t)((bz << 10) + ti) * ROWB;
    const char* gB = reinterpret_cast<const char*>(wsB) + (size_t)((bz << 10) + tj) * ROWB;
    #pragma unroll
    for (int q = 0; q < 4; ++q) {
        const int c = wid * 4 + q;                 // 0..15
        gload_lds16(gA + c * 1024 + lane * 16, reinterpret_cast<char*>(sA) + c * 1024);
        gload_lds16(gB + c * 1024 + lane * 16, reinterpret_cast<char*>(sB) + c * 1024);
    }
    __syncthreads();

    // ---- fragments (XOR-swizzled LDS reads: 2-way banks, free) ----
    const int wr   = (wid >> 1) * 32;   // wave quadrant (32x32) in 64x64 tile
    const int wc   = (wid & 1) * 32;
    const int lrow = lane & 15;
    const int lkb  = lane >> 4;

    half8 afr[2][4], bfr[2][4];
    #pragma unroll
    for (int m = 0; m < 2; ++m)
        #pragma unroll
        for (int t = 0; t < 4; ++t) {
            const int ra = wr + m * 16 + lrow;
            const unsigned Ga = (unsigned)(t * 64 + lkb * 16) ^ (((unsigned)(ra & 7)) << 4);
            afr[m][t] = *reinterpret_cast<const half8*>(
                reinterpret_cast<const char*>(sA) + ra * ROWB + Ga);
            const int rb = wc + m * 16 + lrow;
            const unsigned Gb = (unsigned)(t * 64 + lkb * 16) ^ (((unsigned)(rb & 7)) << 4);
            bfr[m][t] = *reinterpret_cast<const half8*>(
                reinterpret_cast<const char*>(sB) + rb * ROWB + Gb);
        }

    // ---- MFMA + interleaved stores ----
    const int rhi = (lane >> 4) * 4;
    #pragma unroll
    for (int m = 0; m < 2; ++m) {
        floatx4 acc[2];
        #pragma unroll
        for (int n = 0; n < 2; ++n) acc[n] = (floatx4){0.f, 0.f, 0.f, 0.f};
        #pragma unroll
        for (int t = 0; t < 4; ++t)
            #pragma unroll
            for (int n = 0; n < 2; ++n)
                acc[n] = __builtin_amdgcn_mfma_f32_16x16x32_f16(
                    afr[m][t], bfr[n][t], acc[n], 0, 0, 0);
        #pragma unroll
        for (int n = 0; n < 2; ++n) {
            const size_t gj = (size_t)(tj + wc + n * 16 + lrow);
            #pragma unroll
            for (int r = 0; r < 4; ++r) {
                const size_t gi = (size_t)(ti + wr + m * 16 + rhi + r);
                out[((size_t)bz * NPOS + gi) * NPOS + gj] = acc[n][r];
            }
        }
    }
}

// ---------------- fallback: R5 fused kernel (ws too small) ----------------
#define RT  128
#define LDT 136
__global__ __launch_bounds__(256, 1)
void fused_kernel(const float* __restrict__ frac, const float* __restrict__ Wv,
                  const float* __restrict__ bv,   const float* __restrict__ av,
                  float* __restrict__ out) {
    __shared__ _Float16 sA[RT][LDT];
    __shared__ _Float16 sB[RT][LDT];
    __shared__ float    sXA[RT], sXB[RT];
    const int tid = threadIdx.x;
    const int bz  = blockIdx.z;
    const int ti  = blockIdx.y * RT;
    const int tj  = blockIdx.x * RT;
    const float* fb = frac + bz * NPOS;
    if (tid < 128) sXA[tid] = fb[ti + tid];
    else           sXB[tid - 128] = fb[tj + (tid - 128)];
    const int   f      = tid & 63;
    const int   rt4    = tid >> 6;
    const float wf_rev = Wv[f] * (10.0f * INV2PI);
    const float bf_rev = bv[f] * INV2PI;
    const float af     = av[f];
    __syncthreads();
    #pragma unroll
    for (int t = 0; t < 32; ++t) {
        const int row = rt4 + t * 4;
        const float ai = sXA[row] * wf_rev;
        half2x pa;
        pa[0] = (_Float16)__builtin_amdgcn_cosf(ai);
        pa[1] = (_Float16)__builtin_amdgcn_sinf(ai);
        *reinterpret_cast<half2x*>(&sA[row][2 * f]) = pa;
        const float aj = __builtin_fmaf(sXB[row], wf_rev, bf_rev);
        half2x pb;
        pb[0] = (_Float16)(af * __builtin_amdgcn_cosf(aj));
        pb[1] = (_Float16)(af * __builtin_amdgcn_sinf(aj));
        *reinterpret_cast<half2x*>(&sB[row][2 * f]) = pb;
    }
    __syncthreads();
    const int lane = tid & 63, wid = tid >> 6;
    const int wr = (wid >> 1) * 64, wc = (wid & 1) * 64;
    const int lrow = lane & 15, lkb = lane >> 4, rhi = (lane >> 4) * 4;
    half8 bfr[4][4];
    #pragma unroll
    for (int t = 0; t < 4; ++t)
        #pragma unroll
        for (int n = 0; n < 4; ++n)
            bfr[t][n] = *reinterpret_cast<const half8*>(
                &sB[wc + n * 16 + lrow][t * 32 + lkb * 8]);
    #pragma unroll
    for (int m = 0; m < 4; ++m) {
        floatx4 acc[4];
        #pragma unroll
        for (int n = 0; n < 4; ++n) acc[n] = (floatx4){0.f, 0.f, 0.f, 0.f};
        #pragma unroll
        for (int t = 0; t < 4; ++t) {
            const half8 afr = *reinterpret_cast<const half8*>(
                &sA[wr + m * 16 + lrow][t * 32 + lkb * 8]);
            #pragma unroll
            for (int n = 0; n < 4; ++n)
                acc[n] = __builtin_amdgcn_mfma_f32_16x16x32_f16(
                    afr, bfr[t][n], acc[n], 0, 0, 0);
        }
        #pragma unroll
        for (int n = 0; n < 4; ++n) {
            const size_t gj = (size_t)(tj + wc + n * 16 + lrow);
            #pragma unroll
            for (int r = 0; r < 4; ++r) {
                const size_t gi = (size_t)(ti + wr + m * 16 + rhi + r);
                out[((size_t)bz * NPOS + gi) * NPOS + gj] = acc[n][r];
            }
        }
    }
}

extern "C" void kernel_launch(void* const* d_in, const int* in_sizes, int n_in,
                              void* d_out, int out_size, void* d_ws, size_t ws_size,
                              hipStream_t stream) {
    const float* frac = (const float*)d_in[0];  // [4,1024]
    const float* Wv   = (const float*)d_in[1];  // [1,64]
    const float* bv   = (const float*)d_in[2];  // [64]
    const float* av   = (const float*)d_in[3];  // [64]
    float* out = (float*)d_out;                 // [4,1024,1024]

    const size_t need = (size_t)NBATCH * NPOS * ROWB * 2;   // 2 MB
    if (ws_size >= need) {
        _Float16* wsA = (_Float16*)d_ws;
        _Float16* wsB = (_Float16*)((char*)d_ws + need / 2);
        trig_kernel<<<dim3(1024), dim3(256), 0, stream>>>(frac, Wv, bv, av, wsA, wsB);
        gemm_kernel<<<dim3(1024), dim3(256), 0, stream>>>(wsA, wsB, out);
    } else {
        dim3 grid(NPOS / RT, NPOS / RT, NBATCH);
        fused_kernel<<<grid, dim3(256), 0, stream>>>(frac, Wv, bv, av, out);
    }
}

// Round 7
// 12.308 us; speedup vs baseline: 1.3114x; 1.3114x over previous
//
#include <hip/hip_runtime.h>
#include <hip/hip_bf16.h>

#define NPOS   1024
#define NBATCH 4
#define RT     128   // output region per WG (both dims)
#define LDT    136   // sA/sB leading dim in halves (K=128 + 8 pad)
#define CLD    68    // bounce leading dim in floats (64 + 4 pad)

typedef _Float16 half8  __attribute__((ext_vector_type(8)));
typedef _Float16 half2x __attribute__((ext_vector_type(2)));
typedef float    floatx4 __attribute__((ext_vector_type(4)));

#define INV2PI 0.15915494309189535f

// out[b,i,j] = sum_f a_f*cos(10*(x_j-x_i)*w_f + b_f) = <A[i,:], B[j,:]>, K=128
// A[i,2f]=cos(t_i) A[i,2f+1]=sin(t_i); B[j,2f]=a_f cos(t_j+b_f) B[j,2f+1]=a_f sin(..)
// Trig in revolutions (native v_sin/v_cos); |args| <= ~1.8 rev, no reduction.
//
// R7: single fused dispatch (R6 proved each extra dispatch costs ~3us fixed).
// ONE change vs R5: plain stores instead of __builtin_nontemporal_store.
// Output (16.8MB) < aggregate L2 (32MB): let stores retire at L2 speed
// (~0.5us) and let HBM writeback drain asynchronously under the next
// replay's ~8.4us fixed overhead window, instead of forcing the kernel to
// stream to HBM (~2.6us) with the NT hint.
__global__ __launch_bounds__(256, 1)
void fourier_bias_kernel(const float* __restrict__ frac,
                         const float* __restrict__ Wv,
                         const float* __restrict__ bv,
                         const float* __restrict__ av,
                         float* __restrict__ out) {
    __shared__ _Float16 sA[RT][LDT];      // 34.8 KB
    __shared__ _Float16 sB[RT][LDT];      // 34.8 KB
    __shared__ float    sC[4][16][CLD];   // 17.4 KB  per-wave bounce slices
    __shared__ float    sXA[RT], sXB[RT]; // 1 KB

    const int tid = threadIdx.x;
    const int bz  = blockIdx.z;
    const int ti  = blockIdx.y * RT;
    const int tj  = blockIdx.x * RT;

    // ---- phase 0: preload frac rows (one coalesced load) ----
    const float* fb = frac + bz * NPOS;
    if (tid < 128) sXA[tid]       = fb[ti + tid];
    else           sXB[tid - 128] = fb[tj + (tid - 128)];

    const int   f      = tid & 63;
    const int   rt4    = tid >> 6;        // 0..3
    const float wf_rev = Wv[f] * (10.0f * INV2PI);
    const float bf_rev = bv[f] * INV2PI;
    const float af     = av[f];
    __syncthreads();

    // ---- phase 1: trig fill of A/B feature tiles ----
    #pragma unroll
    for (int t = 0; t < 32; ++t) {
        const int row = rt4 + t * 4;      // rows rt4, rt4+4, ..., rt4+124
        const float ai = sXA[row] * wf_rev;
        half2x pa;
        pa[0] = (_Float16)__builtin_amdgcn_cosf(ai);
        pa[1] = (_Float16)__builtin_amdgcn_sinf(ai);
        *reinterpret_cast<half2x*>(&sA[row][2 * f]) = pa;
        const float aj = __builtin_fmaf(sXB[row], wf_rev, bf_rev);
        half2x pb;
        pb[0] = (_Float16)(af * __builtin_amdgcn_cosf(aj));
        pb[1] = (_Float16)(af * __builtin_amdgcn_sinf(aj));
        *reinterpret_cast<half2x*>(&sB[row][2 * f]) = pb;
    }
    __syncthreads();

    // ---- phase 2: per-wave 64x64 quadrant, K=128, f16 MFMA ----
    const int lane = tid & 63;
    const int wid  = tid >> 6;
    const int wr   = (wid >> 1) * 64;     // wave row origin in region
    const int wc   = (wid & 1) * 64;      // wave col origin in region
    const int lrow = lane & 15;
    const int lkb  = lane >> 4;           // k sub-block (8 halves)
    const int rhi  = (lane >> 4) * 4;     // C/D row group

    // hoist all B fragments (16 x half8 = 64 VGPRs)
    half8 bfr[4][4];
    #pragma unroll
    for (int t = 0; t < 4; ++t)
        #pragma unroll
        for (int n = 0; n < 4; ++n)
            bfr[t][n] = *reinterpret_cast<const half8*>(
                &sB[wc + n * 16 + lrow][t * 32 + lkb * 8]);

    #pragma unroll
    for (int m = 0; m < 4; ++m) {         // 16-row m-blocks: compute->store
        floatx4 acc[4];
        #pragma unroll
        for (int n = 0; n < 4; ++n) acc[n] = (floatx4){0.f, 0.f, 0.f, 0.f};

        #pragma unroll
        for (int t = 0; t < 4; ++t) {
            const half8 afr = *reinterpret_cast<const half8*>(
                &sA[wr + m * 16 + lrow][t * 32 + lkb * 8]);
            #pragma unroll
            for (int n = 0; n < 4; ++n)
                acc[n] = __builtin_amdgcn_mfma_f32_16x16x32_f16(
                    afr, bfr[t][n], acc[n], 0, 0, 0);
        }

        // bounce transpose through this wave's private sC slice
        #pragma unroll
        for (int n = 0; n < 4; ++n)
            #pragma unroll
            for (int r = 0; r < 4; ++r)
                sC[wid][rhi + r][n * 16 + lrow] = acc[n][r];

        // each thread stores one float4 of 4 rows (full 128B lines), to L2
        #pragma unroll
        for (int q = 0; q < 4; ++q) {
            const int row16 = q * 4 + (lane >> 4);
            const int c4    = lrow * 4;
            const floatx4 v = *reinterpret_cast<const floatx4*>(&sC[wid][row16][c4]);
            const size_t gi = (size_t)(ti + wr + m * 16 + row16);
            const size_t gj = (size_t)(tj + wc + c4);
            *reinterpret_cast<floatx4*>(out + ((size_t)bz * NPOS + gi) * NPOS + gj) = v;
        }
    }
}

extern "C" void kernel_launch(void* const* d_in, const int* in_sizes, int n_in,
                              void* d_out, int out_size, void* d_ws, size_t ws_size,
                              hipStream_t stream) {
    const float* frac = (const float*)d_in[0];  // [4,1024]
    const float* Wv   = (const float*)d_in[1];  // [1,64]
    const float* bv   = (const float*)d_in[2];  // [64]
    const float* av   = (const float*)d_in[3];  // [64]
    float* out = (float*)d_out;                 // [4,1024,1024]

    dim3 grid(NPOS / RT, NPOS / RT, NBATCH);    // 8 x 8 x 4 = 256 WGs
    fourier_bias_kernel<<<grid, dim3(256), 0, stream>>>(frac, Wv, bv, av, out);
}

// Round 8
// 11.254 us; speedup vs baseline: 1.4342x; 1.0936x over previous
//
#include <hip/hip_runtime.h>
#include <hip/hip_bf16.h>

#define NPOS   1024
#define NBATCH 4
#define RT     128   // output region per WG (both dims)
#define LDT    136   // sA/sB leading dim in halves (K=128 + 8 pad)
#define CLD    68    // bounce leading dim in floats (64 + 4 pad)

typedef _Float16 half8  __attribute__((ext_vector_type(8)));
typedef _Float16 half2x __attribute__((ext_vector_type(2)));
typedef float    floatx4 __attribute__((ext_vector_type(4)));

#define INV2PI 0.15915494309189535f

// out[b,i,j] = sum_f a_f*cos(10*(x_j-x_i)*w_f + b_f) = <A[i,:], B[j,:]>, K=128
// A[i,2f]=cos(t_i) A[i,2f+1]=sin(t_i); B[j,2f]=a_f cos(t_j+b_f) B[j,2f+1]=a_f sin(..)
// Trig in revolutions (native v_sin/v_cos); |args| <= ~1.8 rev, no reduction.
//
// FINAL (== R5, best measured): single fused dispatch; 128x128 region/WG
// (256 WGs, 1/CU); per 16-row m-block MFMA -> per-wave LDS bounce transpose
// -> NONTEMPORAL dwordx4 stores (full 128B lines).
// Measured session facts: per-replay fixed overhead ~8.4us (5.1 graph +
// 3.3/dispatch); this kernel's in-kernel time ~2.8us vs 2.5us HBM-write
// floor (16.8MB @ 6.6TB/s). NT stores beat plain L2-path stores by ~1.1us
// (R7 ablation); multi-dispatch splits lose ~3.3us/extra dispatch (R6).
__global__ __launch_bounds__(256, 1)
void fourier_bias_kernel(const float* __restrict__ frac,
                         const float* __restrict__ Wv,
                         const float* __restrict__ bv,
                         const float* __restrict__ av,
                         float* __restrict__ out) {
    __shared__ _Float16 sA[RT][LDT];      // 34.8 KB
    __shared__ _Float16 sB[RT][LDT];      // 34.8 KB
    __shared__ float    sC[4][16][CLD];   // 17.4 KB  per-wave bounce slices
    __shared__ float    sXA[RT], sXB[RT]; // 1 KB

    const int tid = threadIdx.x;
    const int bz  = blockIdx.z;
    const int ti  = blockIdx.y * RT;
    const int tj  = blockIdx.x * RT;

    // ---- phase 0: preload frac rows (one coalesced load) ----
    const float* fb = frac + bz * NPOS;
    if (tid < 128) sXA[tid]       = fb[ti + tid];
    else           sXB[tid - 128] = fb[tj + (tid - 128)];

    const int   f      = tid & 63;
    const int   rt4    = tid >> 6;        // 0..3
    const float wf_rev = Wv[f] * (10.0f * INV2PI);
    const float bf_rev = bv[f] * INV2PI;
    const float af     = av[f];
    __syncthreads();

    // ---- phase 1: trig fill of A/B feature tiles ----
    #pragma unroll
    for (int t = 0; t < 32; ++t) {
        const int row = rt4 + t * 4;      // rows rt4, rt4+4, ..., rt4+124
        const float ai = sXA[row] * wf_rev;
        half2x pa;
        pa[0] = (_Float16)__builtin_amdgcn_cosf(ai);
        pa[1] = (_Float16)__builtin_amdgcn_sinf(ai);
        *reinterpret_cast<half2x*>(&sA[row][2 * f]) = pa;
        const float aj = __builtin_fmaf(sXB[row], wf_rev, bf_rev);
        half2x pb;
        pb[0] = (_Float16)(af * __builtin_amdgcn_cosf(aj));
        pb[1] = (_Float16)(af * __builtin_amdgcn_sinf(aj));
        *reinterpret_cast<half2x*>(&sB[row][2 * f]) = pb;
    }
    __syncthreads();

    // ---- phase 2: per-wave 64x64 quadrant, K=128, f16 MFMA ----
    const int lane = tid & 63;
    const int wid  = tid >> 6;
    const int wr   = (wid >> 1) * 64;     // wave row origin in region
    const int wc   = (wid & 1) * 64;      // wave col origin in region
    const int lrow = lane & 15;
    const int lkb  = lane >> 4;           // k sub-block (8 halves)
    const int rhi  = (lane >> 4) * 4;     // C/D row group

    // hoist all B fragments (16 x half8 = 64 VGPRs)
    half8 bfr[4][4];
    #pragma unroll
    for (int t = 0; t < 4; ++t)
        #pragma unroll
        for (int n = 0; n < 4; ++n)
            bfr[t][n] = *reinterpret_cast<const half8*>(
                &sB[wc + n * 16 + lrow][t * 32 + lkb * 8]);

    #pragma unroll
    for (int m = 0; m < 4; ++m) {         // 16-row m-blocks: compute->store
        floatx4 acc[4];
        #pragma unroll
        for (int n = 0; n < 4; ++n) acc[n] = (floatx4){0.f, 0.f, 0.f, 0.f};

        #pragma unroll
        for (int t = 0; t < 4; ++t) {
            const half8 afr = *reinterpret_cast<const half8*>(
                &sA[wr + m * 16 + lrow][t * 32 + lkb * 8]);
            #pragma unroll
            for (int n = 0; n < 4; ++n)
                acc[n] = __builtin_amdgcn_mfma_f32_16x16x32_f16(
                    afr, bfr[t][n], acc[n], 0, 0, 0);
        }

        // bounce transpose through this wave's private sC slice
        #pragma unroll
        for (int n = 0; n < 4; ++n)
            #pragma unroll
            for (int r = 0; r < 4; ++r)
                sC[wid][rhi + r][n * 16 + lrow] = acc[n][r];

        // each thread stores one float4 of 4 rows (full 128B lines)
        #pragma unroll
        for (int q = 0; q < 4; ++q) {
            const int row16 = q * 4 + (lane >> 4);
            const int c4    = lrow * 4;
            const floatx4 v = *reinterpret_cast<const floatx4*>(&sC[wid][row16][c4]);
            const size_t gi = (size_t)(ti + wr + m * 16 + row16);
            const size_t gj = (size_t)(tj + wc + c4);
            __builtin_nontemporal_store(
                v, reinterpret_cast<floatx4*>(out + ((size_t)bz * NPOS + gi) * NPOS + gj));
        }
    }
}

extern "C" void kernel_launch(void* const* d_in, const int* in_sizes, int n_in,
                              void* d_out, int out_size, void* d_ws, size_t ws_size,
                              hipStream_t stream) {
    const float* frac = (const float*)d_in[0];  // [4,1024]
    const float* Wv   = (const float*)d_in[1];  // [1,64]
    const float* bv   = (const float*)d_in[2];  // [64]
    const float* av   = (const float*)d_in[3];  // [64]
    float* out = (float*)d_out;                 // [4,1024,1024]

    dim3 grid(NPOS / RT, NPOS / RT, NBATCH);    // 8 x 8 x 4 = 256 WGs
    fourier_bias_kernel<<<grid, dim3(256), 0, stream>>>(frac, Wv, bv, av, out);
}